// Round 7
// baseline (3386.396 us; speedup 1.0000x reference)
//
#include <hip/hip_runtime.h>
#include <hip/hip_bf16.h>
#include <cstdint>
#include <cstddef>

#define B_ 64
#define T_ 512
#define E_ 512
#define H_ 1024
#define V_ 32000
#define BK 64

typedef __attribute__((ext_vector_type(8))) short bf16x8;
typedef __attribute__((ext_vector_type(4))) float f32x4;
typedef __attribute__((ext_vector_type(4))) float float4_t;
typedef unsigned long long ull;
typedef unsigned int u32;

static __device__ __forceinline__ unsigned short f2b(float f) {
  union { float f; u32 u; } v; v.f = f;
  u32 u = v.u;
  u32 r = (u + 0x7FFFu + ((u >> 16) & 1u)) >> 16;  // RNE
  return (unsigned short)r;
}
static __device__ __forceinline__ float b2f(unsigned short s) {
  union { u32 u; float f; } v; v.u = ((u32)s) << 16;
  return v.f;
}
static __device__ __forceinline__ bf16x8 cvt8(const float* p) {
  bf16x8 r;
#pragma unroll
  for (int i = 0; i < 8; i++) r[i] = (short)f2b(p[i]);
  return r;
}
// relaxed agent-scope (sc1) ops: coherent at MALL, no cache maintenance
static __device__ __forceinline__ ull ald(const ull* p) {
  return __hip_atomic_load(p, __ATOMIC_RELAXED, __HIP_MEMORY_SCOPE_AGENT);
}
static __device__ __forceinline__ void ast32(u32* p, u32 v) {
  __hip_atomic_store(p, v, __ATOMIC_RELAXED, __HIP_MEMORY_SCOPE_AGENT);
}
// LDS swizzle for 128-byte rows: spread 16 rows across banks
static __device__ __forceinline__ int swz128(int row, int byte_off) {
  return row * 128 + (byte_off ^ ((row & 7) << 4));
}

// ---------------- init: clear epoch-tagged exchange buffers ----------------
// MUST run every launch (tags from a previous replay would short-circuit the
// waits = forbidden cross-call state). sc1 stores so k_scan's sc1 reads see
// the zeros regardless of XCD/L2 placement.
__global__ void k_init(u32* xb) {
  int i = blockIdx.x * blockDim.x + threadIdx.x;  // 768*256 = 196608 = 3*64*1024
  ast32(xb + i, 0u);
}

// ---------------- E2 = emb @ W_ih^T  [V,H] bf16 ----------------
// grid (16, 500), 256 threads, 64x64 tile, BK=64
__global__ __launch_bounds__(256)
void k_e2(const float* __restrict__ emb, const float* __restrict__ Wih,
          unsigned short* __restrict__ E2) {
  __shared__ unsigned char As[64 * 128];
  __shared__ unsigned char Bs[64 * 128];
  const int tid = threadIdx.x;
  const int lane = tid & 63;
  const int w = tid >> 6;                 // wave id = M sub-tile
  const int n0 = blockIdx.x * 64;         // over H
  const int m0 = blockIdx.y * 64;         // over V
  f32x4 acc[4];
#pragma unroll
  for (int i = 0; i < 4; i++) acc[i] = (f32x4)0.0f;

  for (int kc = 0; kc < E_ / BK; kc++) {
    const int k0 = kc * BK;
    __syncthreads();
#pragma unroll
    for (int it = 0; it < 2; it++) {
      int idx = tid + it * 256;           // 512 chunks of 8
      int r = idx >> 3;                   // 0..63
      int k = (idx & 7) * 8;              // 0..56
      float tmp[8];
      *(float4_t*)(tmp)     = *(const float4_t*)(emb + (size_t)(m0 + r) * E_ + k0 + k);
      *(float4_t*)(tmp + 4) = *(const float4_t*)(emb + (size_t)(m0 + r) * E_ + k0 + k + 4);
      *(bf16x8*)(As + swz128(r, k * 2)) = cvt8(tmp);
      *(float4_t*)(tmp)     = *(const float4_t*)(Wih + (size_t)(n0 + r) * E_ + k0 + k);
      *(float4_t*)(tmp + 4) = *(const float4_t*)(Wih + (size_t)(n0 + r) * E_ + k0 + k + 4);
      *(bf16x8*)(Bs + swz128(r, k * 2)) = cvt8(tmp);
    }
    __syncthreads();
#pragma unroll
    for (int kk = 0; kk < 2; kk++) {
      int kb = kk * 64 + (lane >> 4) * 16;
      bf16x8 a = *(const bf16x8*)(As + swz128(w * 16 + (lane & 15), kb));
#pragma unroll
      for (int nt = 0; nt < 4; nt++) {
        bf16x8 b = *(const bf16x8*)(Bs + swz128(nt * 16 + (lane & 15), kb));
        acc[nt] = __builtin_amdgcn_mfma_f32_16x16x32_bf16(a, b, acc[nt], 0, 0, 0);
      }
    }
  }
#pragma unroll
  for (int nt = 0; nt < 4; nt++) {
#pragma unroll
    for (int reg = 0; reg < 4; reg++) {
      int row = m0 + w * 16 + (lane >> 4) * 4 + reg;
      int col = n0 + nt * 16 + (lane & 15);
      E2[(size_t)row * H_ + col] = f2b(acc[nt][reg]);
    }
  }
}

// ---------------- persistent scan over T ----------------
// 4 independent groups x 16 blocks (R5 partition). Group g owns batch rows
// [16g,16g+16); block j owns h-cols [64j,64j+64), W_hh slice in registers.
// R7: EPOCH-TAGGED exchange. h word = (step+1)<<16 | bf16, stored via sc1.
// The consumer's pull IS the poll: load region, check tags==t, retry if any
// stale. Removes flag store + flag round-trip + vmcnt drains + epilogue
// barrier from the critical path (one MALL round trip per step).
// TRIPLE buffer (proof in analysis): X@t overwrites buf[t%3] whose only
// other readers are pulls(t-2); X@t => producers' pulls(t-1) saw tag t-1
// from ALL blocks => every wave passed pull(t-2). Double-buffer would race.
__global__ __launch_bounds__(256, 1)
void k_scan(const int* __restrict__ hist, const float* __restrict__ Whh,
            const unsigned short* __restrict__ E2,
            u32* __restrict__ xb,         // [3][64][1024] tagged words
            unsigned short* __restrict__ hbf, float* __restrict__ out_h) {
  const int tid = threadIdx.x;
  const int lane = tid & 63;
  const int w = tid >> 6;                 // wave id
  const int bid = blockIdx.x;
  const int g = (bid & 7) >> 1;           // group (batch rows 16g..16g+16)
  const int j = ((bid >> 3) << 1) + (bid & 1);  // col-slice id in [0,16)
  const int row0 = g * 16;                // global batch-row base
  const int col0 = j * 64;                // global col base of this block
  const int wcol0 = col0 + w * 16;        // this wave's 16 cols

  __shared__ unsigned char hs[2][16 * 2048];  // bf16 h slice, dbuf by t&1

  const int ar = lane & 15;               // row-in-16 / MFMA A-row
  const int hi = lane >> 4;               // 0..3
  const int swb = (ar & 7) << 4;          // row XOR swizzle

  // B-frags: lane holds W_hh[wcol0+ar][kk*32 + hi*8 + 0..8)
  bf16x8 Breg[32];
  {
    const float* wrow = Whh + (size_t)(wcol0 + ar) * H_ + hi * 8;
#pragma unroll
    for (int kk = 0; kk < 32; kk++) {
      float tmp[8];
      *(float4_t*)(tmp)     = *(const float4_t*)(wrow + kk * 32);
      *(float4_t*)(tmp + 4) = *(const float4_t*)(wrow + kk * 32 + 4);
      Breg[kk] = cvt8(tmp);
    }
  }

  for (int t = 0; t < T_; t++) {
    // xi gather (plain cached loads, read-only data), issued early
    float xiv[4];
    {
      int tok[4];
#pragma unroll
      for (int r = 0; r < 4; r++)
        tok[r] = hist[(size_t)(row0 + hi * 4 + r) * T_ + t];
#pragma unroll
      for (int r = 0; r < 4; r++)
        xiv[r] = b2f(E2[(size_t)tok[r] * H_ + wcol0 + ar]);
    }

    f32x4 acc0 = (f32x4)0.0f, acc1 = (f32x4)0.0f;

    if (t > 0) {
      // ---- self-validating pull: wave w reads rows 0..15 x cols
      // [256w,256w+256) of buf[(t-1)%3]; lane (ar,hi): row ar, words
      // i*8+hi*2 (+1) of the 256-col range, as 32x 8B sc1 loads. ----
      const ull* src = (const ull*)(xb + (size_t)((t + 2) % 3) * (B_ * H_) +
                                    (size_t)(row0 + ar) * H_ + 256 * w);
      const u32 tagv = (u32)t << 16;
      ull hv[32];
      for (;;) {
        #pragma unroll
        for (int i = 0; i < 32; i++) hv[i] = ald(src + i * 4 + hi);
        u32 bad = 0;
        #pragma unroll
        for (int i = 0; i < 32; i++) {
          u32 a = (u32)hv[i], b = (u32)(hv[i] >> 32);
          bad |= ((a ^ tagv) | (b ^ tagv)) & 0xFFFF0000u;
        }
        if (__all(bad == 0)) break;
        __builtin_amdgcn_s_sleep(1);
      }
      // pack tagged pairs -> bf16x2 dwords into LDS (swizzled)
      {
        unsigned char* hsb = hs[t & 1] + ar * 2048;
        #pragma unroll
        for (int i = 0; i < 32; i++) {
          u32 p = ((u32)hv[i] & 0xFFFFu) | ((u32)(hv[i] >> 32) << 16);
          *(u32*)(hsb + ((512 * w + i * 16 + hi * 4) ^ swb)) = p;
        }
      }
      __syncthreads();

      // C[16x16] = h[16x1024] @ Wslice[16x1024]^T
      const unsigned char* arow_l = hs[t & 1] + ar * 2048;
      #pragma unroll
      for (int kk = 0; kk < 32; kk += 2) {
        bf16x8 a0 = *(const bf16x8*)(arow_l + (((kk)     * 64 + hi * 16) ^ swb));
        bf16x8 a1 = *(const bf16x8*)(arow_l + (((kk + 1) * 64 + hi * 16) ^ swb));
        acc0 = __builtin_amdgcn_mfma_f32_16x16x32_bf16(a0, Breg[kk],     acc0, 0, 0, 0);
        acc1 = __builtin_amdgcn_mfma_f32_16x16x32_bf16(a1, Breg[kk + 1], acc1, 0, 0, 0);
      }
    }

    // epilogue: tanh, tagged store (no drain, no barrier — store IS signal)
    u32* dst = xb + (size_t)(t % 3) * (B_ * H_);
    const u32 tagw = (u32)(t + 1) << 16;
#pragma unroll
    for (int reg = 0; reg < 4; reg++) {
      const int row = row0 + hi * 4 + reg;
      float pre = acc0[reg] + acc1[reg] + xiv[reg];
      float hval = tanhf(pre);
      ast32(dst + (size_t)row * H_ + wcol0 + ar, tagw | (u32)f2b(hval));
      if (t == T_ - 1) {
        hbf[(size_t)row * H_ + wcol0 + ar] = f2b(hval);    // for k_logits
        out_h[(size_t)row * H_ + wcol0 + ar] = hval;       // fp32 output
      }
    }
  }
}

// ---------------- logits = h_final @ W_cls^T + b ----------------
// grid 500 blocks (64 vocab cols each), 256 threads
__global__ __launch_bounds__(256)
void k_logits(const unsigned short* __restrict__ hb,
              const float* __restrict__ Wcls, const float* __restrict__ bcls,
              float* __restrict__ out) {
  __shared__ unsigned char Bs[64 * 128];
  const int tid = threadIdx.x;
  const int lane = tid & 63;
  const int w = tid >> 6;
  const int n0 = blockIdx.x * 64;
  f32x4 acc[4];
#pragma unroll
  for (int i = 0; i < 4; i++) acc[i] = (f32x4)0.0f;

  for (int kc = 0; kc < H_ / BK; kc++) {
    const int k0 = kc * BK;
    __syncthreads();
#pragma unroll
    for (int it = 0; it < 2; it++) {
      int idx = tid + it * 256;
      int r = idx >> 3;
      int k = (idx & 7) * 8;
      float tmp[8];
      *(float4_t*)(tmp)     = *(const float4_t*)(Wcls + (size_t)(n0 + r) * H_ + k0 + k);
      *(float4_t*)(tmp + 4) = *(const float4_t*)(Wcls + (size_t)(n0 + r) * H_ + k0 + k + 4);
      *(bf16x8*)(Bs + swz128(r, k * 2)) = cvt8(tmp);
    }
    __syncthreads();
#pragma unroll
    for (int kk = 0; kk < 2; kk++) {
      const unsigned short* ap =
          hb + (size_t)(w * 16 + (lane & 15)) * H_ + k0 + kk * 32 + (lane >> 4) * 8;
      bf16x8 a = *(const bf16x8*)ap;
      int kb = kk * 64 + (lane >> 4) * 16;
#pragma unroll
      for (int nt = 0; nt < 4; nt++) {
        bf16x8 b = *(const bf16x8*)(Bs + swz128(nt * 16 + (lane & 15), kb));
        acc[nt] = __builtin_amdgcn_mfma_f32_16x16x32_bf16(a, b, acc[nt], 0, 0, 0);
      }
    }
  }
#pragma unroll
  for (int nt = 0; nt < 4; nt++) {
    int col = n0 + nt * 16 + (lane & 15);
    float bias = bcls[col];
#pragma unroll
    for (int reg = 0; reg < 4; reg++) {
      int row = w * 16 + (lane >> 4) * 4 + reg;
      out[(size_t)row * V_ + col] = acc[nt][reg] + bias;
    }
  }
}

extern "C" void kernel_launch(void* const* d_in, const int* in_sizes, int n_in,
                              void* d_out, int out_size, void* d_ws, size_t ws_size,
                              hipStream_t stream) {
  const int*   hist = (const int*)d_in[0];
  const float* emb  = (const float*)d_in[1];
  const float* Wih  = (const float*)d_in[2];
  const float* Whh  = (const float*)d_in[3];
  const float* Wcls = (const float*)d_in[4];
  const float* bcls = (const float*)d_in[5];
  float* out = (float*)d_out;

  unsigned char* ws = (unsigned char*)d_ws;
  const size_t E2_BYTES = (size_t)V_ * H_ * 2;        // 65,536,000
  const size_t XB_BYTES = (size_t)3 * B_ * H_ * 4;    // 786,432
  unsigned short* E2  = (unsigned short*)ws;
  u32*            xbf = (u32*)(ws + E2_BYTES);
  unsigned short* hbf = (unsigned short*)(ws + E2_BYTES + XB_BYTES);

  k_init<<<768, 256, 0, stream>>>(xbf);
  k_e2<<<dim3(16, 500), 256, 0, stream>>>(emb, Wih, E2);
  k_scan<<<64, 256, 0, stream>>>(hist, Whh, E2, xbf, hbf,
                                 out + (size_t)B_ * V_);
  k_logits<<<500, 256, 0, stream>>>(hbf, Wcls, bcls, out);
}

// Round 9
// 2329.950 us; speedup vs baseline: 1.4534x; 1.4534x over previous
//
#include <hip/hip_runtime.h>
#include <hip/hip_bf16.h>
#include <cstdint>
#include <cstddef>

#define B_ 64
#define T_ 512
#define E_ 512
#define H_ 1024
#define V_ 32000
#define BK 64

typedef __attribute__((ext_vector_type(8))) short bf16x8;
typedef __attribute__((ext_vector_type(4))) float f32x4;
typedef __attribute__((ext_vector_type(4))) float float4_t;
typedef unsigned long long ull;
typedef unsigned int u32;

static __device__ __forceinline__ unsigned short f2b(float f) {
  union { float f; u32 u; } v; v.f = f;
  u32 u = v.u;
  u32 r = (u + 0x7FFFu + ((u >> 16) & 1u)) >> 16;  // RNE
  return (unsigned short)r;
}
static __device__ __forceinline__ float b2f(unsigned short s) {
  union { u32 u; float f; } v; v.u = ((u32)s) << 16;
  return v.f;
}
static __device__ __forceinline__ bf16x8 cvt8(const float* p) {
  bf16x8 r;
#pragma unroll
  for (int i = 0; i < 8; i++) r[i] = (short)f2b(p[i]);
  return r;
}
static __device__ __forceinline__ bf16x8 mk8(ull lo, ull hi) {
  union { ull u[2]; bf16x8 v; } c; c.u[0] = lo; c.u[1] = hi; return c.v;
}
// relaxed agent-scope (sc1) ops: coherent at MALL, no cache maintenance
static __device__ __forceinline__ ull ald(const ull* p) {
  return __hip_atomic_load(p, __ATOMIC_RELAXED, __HIP_MEMORY_SCOPE_AGENT);
}
static __device__ __forceinline__ u32 ald32(const u32* p) {
  return __hip_atomic_load(p, __ATOMIC_RELAXED, __HIP_MEMORY_SCOPE_AGENT);
}
static __device__ __forceinline__ void ast64(ull* p, ull v) {
  __hip_atomic_store(p, v, __ATOMIC_RELAXED, __HIP_MEMORY_SCOPE_AGENT);
}
static __device__ __forceinline__ void ast32(u32* p, u32 v) {
  __hip_atomic_store(p, v, __ATOMIC_RELAXED, __HIP_MEMORY_SCOPE_AGENT);
}
// LDS swizzle for 128-byte rows: spread rows across banks
static __device__ __forceinline__ int swz128(int row, int byte_off) {
  return row * 128 + (byte_off ^ ((row & 7) << 4));
}

#define NFLAGS 256

// ---------------- init: clear flags ----------------
// MUST run every launch (replay would otherwise see stale flags).
__global__ void k_init(u32* flags) {
  int i = threadIdx.x;
  if (i < NFLAGS) ast32(&flags[i], 0u);
}

// ---------------- E2 = emb @ W_ih^T  [V,H] bf16 ----------------
// grid (16, 500), 256 threads, 64x64 tile, BK=64
__global__ __launch_bounds__(256)
void k_e2(const float* __restrict__ emb, const float* __restrict__ Wih,
          unsigned short* __restrict__ E2) {
  __shared__ unsigned char As[64 * 128];
  __shared__ unsigned char Bs[64 * 128];
  const int tid = threadIdx.x;
  const int lane = tid & 63;
  const int w = tid >> 6;
  const int n0 = blockIdx.x * 64;
  const int m0 = blockIdx.y * 64;
  f32x4 acc[4];
#pragma unroll
  for (int i = 0; i < 4; i++) acc[i] = (f32x4)0.0f;

  for (int kc = 0; kc < E_ / BK; kc++) {
    const int k0 = kc * BK;
    __syncthreads();
#pragma unroll
    for (int it = 0; it < 2; it++) {
      int idx = tid + it * 256;
      int r = idx >> 3;
      int k = (idx & 7) * 8;
      float tmp[8];
      *(float4_t*)(tmp)     = *(const float4_t*)(emb + (size_t)(m0 + r) * E_ + k0 + k);
      *(float4_t*)(tmp + 4) = *(const float4_t*)(emb + (size_t)(m0 + r) * E_ + k0 + k + 4);
      *(bf16x8*)(As + swz128(r, k * 2)) = cvt8(tmp);
      *(float4_t*)(tmp)     = *(const float4_t*)(Wih + (size_t)(n0 + r) * E_ + k0 + k);
      *(float4_t*)(tmp + 4) = *(const float4_t*)(Wih + (size_t)(n0 + r) * E_ + k0 + k + 4);
      *(bf16x8*)(Bs + swz128(r, k * 2)) = cvt8(tmp);
    }
    __syncthreads();
#pragma unroll
    for (int kk = 0; kk < 2; kk++) {
      int kb = kk * 64 + (lane >> 4) * 16;
      bf16x8 a = *(const bf16x8*)(As + swz128(w * 16 + (lane & 15), kb));
#pragma unroll
      for (int nt = 0; nt < 4; nt++) {
        bf16x8 b = *(const bf16x8*)(Bs + swz128(nt * 16 + (lane & 15), kb));
        acc[nt] = __builtin_amdgcn_mfma_f32_16x16x32_bf16(a, b, acc[nt], 0, 0, 0);
      }
    }
  }
#pragma unroll
  for (int nt = 0; nt < 4; nt++) {
#pragma unroll
    for (int reg = 0; reg < 4; reg++) {
      int row = m0 + w * 16 + (lane >> 4) * 4 + reg;
      int col = n0 + nt * 16 + (lane & 15);
      E2[(size_t)row * H_ + col] = f2b(acc[nt][reg]);
    }
  }
}

// ---------------- persistent scan over T ----------------
// R5 champion structure, exactly: 4 independent groups x 16 blocks. Group g
// owns batch rows [16g,16g+16); block j owns h-cols [64j,64j+64), W_hh slice
// in registers; per-step the block pulls the group's 32KB h slice (wave w
// pulls K-chunks [8w,8w+8), shares via LDS), 2 barriers/step, per-group
// 16-flag line, sc1 everywhere, producer drain -> barrier -> flag.
// R9 change: MFMA operands SWAPPED (A = W-frag from regs, B = h-frag from
// LDS) so D[m=outcol][n=batch]: lane (b=lane&15, q=lane>>4) holds 4
// CONSECUTIVE output cols (wcol0+q*4+reg) of batch row (row0+b) ->
//   - h store: one 8B sc1 store  (was 4x 2B strided)
//   - xi load: one 8B load       (was 4x 2B strided)
//   - out_h:   one 16B store     (was 4x 4B strided)
// Both fragments already have lane&15 = own-row layout, so staging, swizzle,
// and Wreg layout are byte-identical to R5 — no new sync/race surface.
__global__ __launch_bounds__(256, 1)
void k_scan(const int* __restrict__ hist, const float* __restrict__ Whh,
            const unsigned short* __restrict__ E2,
            unsigned short* __restrict__ hb0, unsigned short* __restrict__ hb1,
            u32* __restrict__ flags, float* __restrict__ out_h) {
  const int tid = threadIdx.x;
  const int lane = tid & 63;
  const int w = tid >> 6;                 // wave id
  const int bid = blockIdx.x;
  const int g = (bid & 7) >> 1;           // group (batch rows 16g..16g+16)
  const int j = ((bid >> 3) << 1) + (bid & 1);  // col-slice id in [0,16)
  const int row0 = g * 16;                // global batch-row base
  const int wcol0 = j * 64 + w * 16;      // this wave's 16 output cols

  __shared__ unsigned char hs[16 * 2048]; // h slice [16 rows][1024] swizzled

  const int ar = lane & 15;               // fragment row (batch row AND W row)
  const int hi = lane >> 4;               // 0..3
  const int swb = (ar & 7) << 4;          // row XOR swizzle

  // W-frags (MFMA A operand): lane holds W_hh[wcol0+ar][kk*32 + hi*8 + 0..8)
  bf16x8 Wreg[32];
  {
    const float* wrow = Whh + (size_t)(wcol0 + ar) * H_ + hi * 8;
#pragma unroll
    for (int kk = 0; kk < 32; kk++) {
      float tmp[8];
      *(float4_t*)(tmp)     = *(const float4_t*)(wrow + kk * 32);
      *(float4_t*)(tmp + 4) = *(const float4_t*)(wrow + kk * 32 + 4);
      Wreg[kk] = cvt8(tmp);
    }
  }

  u32* gflags = flags + g * 16;           // one 64B line per group

  for (int t = 0; t < T_; t++) {
    const unsigned short* hc = (t & 1) ? hb1 : hb0;
    unsigned short*       hn = (t & 1) ? hb0 : hb1;

    // xi gather: ONE 8B load per lane — E2[tok][wcol0 + q*4 .. +4)
    float xiv[4];
    {
      const int tok = hist[(size_t)(row0 + ar) * T_ + t];
      const ull xw = *(const ull*)(E2 + (size_t)tok * H_ + wcol0 + hi * 4);
      xiv[0] = b2f((unsigned short)xw);
      xiv[1] = b2f((unsigned short)(xw >> 16));
      xiv[2] = b2f((unsigned short)(xw >> 32));
      xiv[3] = b2f((unsigned short)(xw >> 48));
    }

    f32x4 acc0 = (f32x4)0.0f, acc1 = (f32x4)0.0f;

    if (t > 0) {
      // wait for this group's 16 producers (one 64B line, R5-proven)
      const u32 e = (u32)t;
      for (;;) {
        u32 f = ald32(&gflags[ar]);
        if (__all(f >= e)) break;
        __builtin_amdgcn_s_sleep(1);
      }
      asm volatile("" ::: "memory");      // keep h loads below the poll

      // pull h slice: wave w fetches K-chunks [8w, 8w+8): lane (ar,hi) ->
      // row ar, 16B at byte kk*64 + hi*16. Fully coalesced.
      {
        const ull* hrow = (const ull*)(hc + (size_t)(row0 + ar) * H_);
        ull hv[16];
#pragma unroll
        for (int c = 0; c < 8; c++) {
          const int kk = w * 8 + c;
          hv[2 * c]     = ald(hrow + kk * 8 + hi * 2);
          hv[2 * c + 1] = ald(hrow + kk * 8 + hi * 2 + 1);
        }
        unsigned char* hsb = hs + ar * 2048;
#pragma unroll
        for (int c = 0; c < 8; c++) {
          const int kk = w * 8 + c;
          *(bf16x8*)(hsb + ((kk * 64 + hi * 16) ^ swb)) =
              mk8(hv[2 * c], hv[2 * c + 1]);
        }
      }
      __syncthreads();

      // D[m=outcol][n=batch] = sum_k W[outcol][k] * h[batch][k]
      // A = Wreg (lane&15 = W row = outcol), B = h-frag (lane&15 = batch row)
      const unsigned char* arow_l = hs + ar * 2048;
#pragma unroll
      for (int kk = 0; kk < 32; kk += 2) {
        bf16x8 b0 = *(const bf16x8*)(arow_l + (((kk)     * 64 + hi * 16) ^ swb));
        bf16x8 b1 = *(const bf16x8*)(arow_l + (((kk + 1) * 64 + hi * 16) ^ swb));
        acc0 = __builtin_amdgcn_mfma_f32_16x16x32_bf16(Wreg[kk],     b0, acc0, 0, 0, 0);
        acc1 = __builtin_amdgcn_mfma_f32_16x16x32_bf16(Wreg[kk + 1], b1, acc1, 0, 0, 0);
      }
    }

    // epilogue: lane (b=ar, q=hi) owns h_next[row0+b][wcol0+q*4 .. +4)
    {
      float hval[4];
#pragma unroll
      for (int reg = 0; reg < 4; reg++)
        hval[reg] = tanhf(acc0[reg] + acc1[reg] + xiv[reg]);
      ull hw = (ull)f2b(hval[0]) | ((ull)f2b(hval[1]) << 16) |
               ((ull)f2b(hval[2]) << 32) | ((ull)f2b(hval[3]) << 48);
      ast64((ull*)(hn + (size_t)(row0 + ar) * H_ + wcol0 + hi * 4), hw);
      if (t == T_ - 1) {
        float4_t o = {hval[0], hval[1], hval[2], hval[3]};
        *(float4_t*)(out_h + (size_t)(row0 + ar) * H_ + wcol0 + hi * 4) = o;
      }
    }

    // order: drain own stores, block barrier, signal (R5-proven)
    asm volatile("s_waitcnt vmcnt(0)" ::: "memory");
    __syncthreads();
    if (tid == 0)
      ast32(&gflags[j], (u32)(t + 1));
  }
}

// ---------------- logits = h_final @ W_cls^T + b ----------------
// grid 500 blocks (64 vocab cols each), 256 threads
__global__ __launch_bounds__(256)
void k_logits(const unsigned short* __restrict__ hb,
              const float* __restrict__ Wcls, const float* __restrict__ bcls,
              float* __restrict__ out) {
  __shared__ unsigned char Bs[64 * 128];
  const int tid = threadIdx.x;
  const int lane = tid & 63;
  const int w = tid >> 6;
  const int n0 = blockIdx.x * 64;
  f32x4 acc[4];
#pragma unroll
  for (int i = 0; i < 4; i++) acc[i] = (f32x4)0.0f;

  for (int kc = 0; kc < H_ / BK; kc++) {
    const int k0 = kc * BK;
    __syncthreads();
#pragma unroll
    for (int it = 0; it < 2; it++) {
      int idx = tid + it * 256;
      int r = idx >> 3;
      int k = (idx & 7) * 8;
      float tmp[8];
      *(float4_t*)(tmp)     = *(const float4_t*)(Wcls + (size_t)(n0 + r) * H_ + k0 + k);
      *(float4_t*)(tmp + 4) = *(const float4_t*)(Wcls + (size_t)(n0 + r) * H_ + k0 + k + 4);
      *(bf16x8*)(Bs + swz128(r, k * 2)) = cvt8(tmp);
    }
    __syncthreads();
#pragma unroll
    for (int kk = 0; kk < 2; kk++) {
      const unsigned short* ap =
          hb + (size_t)(w * 16 + (lane & 15)) * H_ + k0 + kk * 32 + (lane >> 4) * 8;
      bf16x8 a = *(const bf16x8*)ap;
      int kb = kk * 64 + (lane >> 4) * 16;
#pragma unroll
      for (int nt = 0; nt < 4; nt++) {
        bf16x8 b = *(const bf16x8*)(Bs + swz128(nt * 16 + (lane & 15), kb));
        acc[nt] = __builtin_amdgcn_mfma_f32_16x16x32_bf16(a, b, acc[nt], 0, 0, 0);
      }
    }
  }
#pragma unroll
  for (int nt = 0; nt < 4; nt++) {
    int col = n0 + nt * 16 + (lane & 15);
    float bias = bcls[col];
#pragma unroll
    for (int reg = 0; reg < 4; reg++) {
      int row = w * 16 + (lane >> 4) * 4 + reg;
      out[(size_t)row * V_ + col] = acc[nt][reg] + bias;
    }
  }
}

extern "C" void kernel_launch(void* const* d_in, const int* in_sizes, int n_in,
                              void* d_out, int out_size, void* d_ws, size_t ws_size,
                              hipStream_t stream) {
  const int*   hist = (const int*)d_in[0];
  const float* emb  = (const float*)d_in[1];
  const float* Wih  = (const float*)d_in[2];
  const float* Whh  = (const float*)d_in[3];
  const float* Wcls = (const float*)d_in[4];
  const float* bcls = (const float*)d_in[5];
  float* out = (float*)d_out;

  unsigned char* ws = (unsigned char*)d_ws;
  const size_t E2_BYTES = (size_t)V_ * H_ * 2;        // 65,536,000
  const size_t HB_BYTES = (size_t)B_ * H_ * 2;        // 131,072
  unsigned short* E2    = (unsigned short*)ws;
  unsigned short* hb0   = (unsigned short*)(ws + E2_BYTES);
  unsigned short* hb1   = (unsigned short*)(ws + E2_BYTES + HB_BYTES);
  u32*            flags = (u32*)(ws + E2_BYTES + 2 * HB_BYTES);

  k_init<<<1, 256, 0, stream>>>(flags);
  k_e2<<<dim3(16, 500), 256, 0, stream>>>(emb, Wih, E2);
  // T_=512: last write (t=511, odd) lands in hb0 -> k_logits reads hb0
  k_scan<<<64, 256, 0, stream>>>(hist, Whh, E2, hb0, hb1, flags,
                                 out + (size_t)B_ * V_);
  k_logits<<<500, 256, 0, stream>>>(hb0, Wcls, bcls, out);
}

// Round 10
// 1634.486 us; speedup vs baseline: 2.0718x; 1.4255x over previous
//
#include <hip/hip_runtime.h>
#include <hip/hip_bf16.h>
#include <cstdint>
#include <cstddef>

#define B_ 64
#define T_ 512
#define E_ 512
#define H_ 1024
#define V_ 32000
#define BK 64

typedef __attribute__((ext_vector_type(8))) short bf16x8;
typedef __attribute__((ext_vector_type(4))) float f32x4;
typedef __attribute__((ext_vector_type(4))) float float4_t;
typedef unsigned long long ull;
typedef unsigned int u32;

static __device__ __forceinline__ unsigned short f2b(float f) {
  union { float f; u32 u; } v; v.f = f;
  u32 u = v.u;
  u32 r = (u + 0x7FFFu + ((u >> 16) & 1u)) >> 16;  // RNE
  return (unsigned short)r;
}
static __device__ __forceinline__ float b2f(unsigned short s) {
  union { u32 u; float f; } v; v.u = ((u32)s) << 16;
  return v.f;
}
static __device__ __forceinline__ bf16x8 cvt8(const float* p) {
  bf16x8 r;
#pragma unroll
  for (int i = 0; i < 8; i++) r[i] = (short)f2b(p[i]);
  return r;
}
// relaxed agent-scope (sc1) ops: coherent at MALL, no cache maintenance
static __device__ __forceinline__ ull ald(const ull* p) {
  return __hip_atomic_load(p, __ATOMIC_RELAXED, __HIP_MEMORY_SCOPE_AGENT);
}
static __device__ __forceinline__ u32 ald32(const u32* p) {
  return __hip_atomic_load(p, __ATOMIC_RELAXED, __HIP_MEMORY_SCOPE_AGENT);
}
static __device__ __forceinline__ void ast64(ull* p, ull v) {
  __hip_atomic_store(p, v, __ATOMIC_RELAXED, __HIP_MEMORY_SCOPE_AGENT);
}
static __device__ __forceinline__ void ast32(u32* p, u32 v) {
  __hip_atomic_store(p, v, __ATOMIC_RELAXED, __HIP_MEMORY_SCOPE_AGENT);
}
// LDS swizzle for 128-byte rows: spread rows across banks
static __device__ __forceinline__ int swz128(int row, int byte_off) {
  return row * 128 + (byte_off ^ ((row & 7) << 4));
}

#define NFLAGS 256

// ---------------- init: clear flags ----------------
// MUST run every launch (replay would otherwise see stale flags).
__global__ void k_init(u32* flags) {
  int i = threadIdx.x;
  if (i < NFLAGS) ast32(&flags[i], 0u);
}

// ---------------- E2 = emb @ W_ih^T  [V,H] bf16 ----------------
// grid (16, 500), 256 threads, 64x64 tile, BK=64
__global__ __launch_bounds__(256)
void k_e2(const float* __restrict__ emb, const float* __restrict__ Wih,
          unsigned short* __restrict__ E2) {
  __shared__ unsigned char As[64 * 128];
  __shared__ unsigned char Bs[64 * 128];
  const int tid = threadIdx.x;
  const int lane = tid & 63;
  const int w = tid >> 6;
  const int n0 = blockIdx.x * 64;
  const int m0 = blockIdx.y * 64;
  f32x4 acc[4];
#pragma unroll
  for (int i = 0; i < 4; i++) acc[i] = (f32x4)0.0f;

  for (int kc = 0; kc < E_ / BK; kc++) {
    const int k0 = kc * BK;
    __syncthreads();
#pragma unroll
    for (int it = 0; it < 2; it++) {
      int idx = tid + it * 256;
      int r = idx >> 3;
      int k = (idx & 7) * 8;
      float tmp[8];
      *(float4_t*)(tmp)     = *(const float4_t*)(emb + (size_t)(m0 + r) * E_ + k0 + k);
      *(float4_t*)(tmp + 4) = *(const float4_t*)(emb + (size_t)(m0 + r) * E_ + k0 + k + 4);
      *(bf16x8*)(As + swz128(r, k * 2)) = cvt8(tmp);
      *(float4_t*)(tmp)     = *(const float4_t*)(Wih + (size_t)(n0 + r) * E_ + k0 + k);
      *(float4_t*)(tmp + 4) = *(const float4_t*)(Wih + (size_t)(n0 + r) * E_ + k0 + k + 4);
      *(bf16x8*)(Bs + swz128(r, k * 2)) = cvt8(tmp);
    }
    __syncthreads();
#pragma unroll
    for (int kk = 0; kk < 2; kk++) {
      int kb = kk * 64 + (lane >> 4) * 16;
      bf16x8 a = *(const bf16x8*)(As + swz128(w * 16 + (lane & 15), kb));
#pragma unroll
      for (int nt = 0; nt < 4; nt++) {
        bf16x8 b = *(const bf16x8*)(Bs + swz128(nt * 16 + (lane & 15), kb));
        acc[nt] = __builtin_amdgcn_mfma_f32_16x16x32_bf16(a, b, acc[nt], 0, 0, 0);
      }
    }
  }
#pragma unroll
  for (int nt = 0; nt < 4; nt++) {
#pragma unroll
    for (int reg = 0; reg < 4; reg++) {
      int row = m0 + w * 16 + (lane >> 4) * 4 + reg;
      int col = n0 + nt * 16 + (lane & 15);
      E2[(size_t)row * H_ + col] = f2b(acc[nt][reg]);
    }
  }
}

// ---------------- persistent scan over T ----------------
// R10 geometry: 8 independent groups x 8 blocks x 8 waves (512 thr).
// Group g (= bid&7, one XCD under round-robin for L2 sharing of E2 reads)
// owns batch rows [8g,8g+8); block j (= bid>>3) owns h-cols [128j,128j+128);
// wave w owns 16 cols (Wreg = 32 x bf16x8 = 128 VGPR, as R9).
// Per step: pull 16KB (wave w pulls row w: 2KB, 4x8B/lane coalesced);
// poll 8 producers (one 64B flag line). Protocol byte-identical to R5/R9:
// sc1 relaxed atomics; store -> vmcnt(0) -> barrier -> tid0 flag ->
// consumer poll -> pull. NO new visibility assumptions (R8 lesson).
// Single-buffer LDS safety: stage(t+1) follows poll(t+1) => all blocks'
// flag(t) => own barrier#2(t) => all waves' MFMA(t) done. Same chain is
// the global h WAR guard (R5-proven).
// MFMA: D[m=outcol][n=batch], A=Wreg, B=h-frag; n>=8 lanes compute discarded
// duplicates (rows a7) — finite garbage, per-element independent.
__global__ __launch_bounds__(512, 1)
void k_scan(const int* __restrict__ hist, const float* __restrict__ Whh,
            const unsigned short* __restrict__ E2,
            unsigned short* __restrict__ hb0, unsigned short* __restrict__ hb1,
            u32* __restrict__ flags, float* __restrict__ out_h) {
  const int tid = threadIdx.x;
  const int lane = tid & 63;
  const int w = tid >> 6;                 // wave id 0..7
  const int bid = blockIdx.x;
  const int g = bid & 7;                  // group (batch rows 8g..8g+8)
  const int j = bid >> 3;                 // col-slice id 0..7
  const int row0 = g * 8;                 // global batch-row base
  const int wcol0 = j * 128 + w * 16;     // this wave's 16 output cols

  __shared__ unsigned char hs[8 * 2048];  // h slice [8 rows][1024] swizzled

  const int ar = lane & 15;               // frag row: outcol (A) / batch (B,D)
  const int a7 = ar & 7;                  // valid batch row index
  const int hi = lane >> 4;               // 0..3 k-group

  // W-frags (MFMA A): lane holds W_hh[wcol0+ar][kk*32 + hi*8 .. +8)
  bf16x8 Wreg[32];
  {
    const float* wrow = Whh + (size_t)(wcol0 + ar) * H_ + hi * 8;
#pragma unroll
    for (int kk = 0; kk < 32; kk++) {
      float tmp[8];
      *(float4_t*)(tmp)     = *(const float4_t*)(wrow + kk * 32);
      *(float4_t*)(tmp + 4) = *(const float4_t*)(wrow + kk * 32 + 4);
      Wreg[kk] = cvt8(tmp);
    }
  }

  u32* gflags = flags + g * 16;           // one 64B line per group

  for (int t = 0; t < T_; t++) {
    const unsigned short* hc = (t & 1) ? hb1 : hb0;   // h(t-1)
    unsigned short*       hn = (t & 1) ? hb0 : hb1;   // h(t); t=511 -> hb0

    // xi gather: ONE 8B load per lane — E2[tok][wcol0 + hi*4 .. +4)
    float xiv[4];
    {
      const int tok = hist[(size_t)(row0 + a7) * T_ + t];
      const ull xw = *(const ull*)(E2 + (size_t)tok * H_ + wcol0 + hi * 4);
      xiv[0] = b2f((unsigned short)xw);
      xiv[1] = b2f((unsigned short)(xw >> 16));
      xiv[2] = b2f((unsigned short)(xw >> 32));
      xiv[3] = b2f((unsigned short)(xw >> 48));
    }

    f32x4 acc0 = (f32x4)0.0f, acc1 = (f32x4)0.0f;

    if (t > 0) {
      // wait for this group's 8 producers (one 64B line)
      const u32 e = (u32)t;
      for (;;) {
        u32 f = ald32(&gflags[lane & 7]);
        if (__all(f >= e)) break;
        __builtin_amdgcn_s_sleep(1);
      }
      asm volatile("" ::: "memory");      // keep h loads below the poll

      // pull h slice: wave w pulls row w (2KB): lane covers ull lane+64i
      {
        const ull* hrow = (const ull*)(hc + (size_t)(row0 + w) * H_);
        ull h0 = ald(hrow + lane);
        ull h1 = ald(hrow + lane + 64);
        ull h2 = ald(hrow + lane + 128);
        ull h3 = ald(hrow + lane + 192);
        unsigned char* hsb = hs + w * 2048;
        const int sw = w << 4;            // row-keyed XOR swizzle
        *(ull*)(hsb + ((lane * 8)        ^ sw)) = h0;
        *(ull*)(hsb + ((lane * 8 + 512)  ^ sw)) = h1;
        *(ull*)(hsb + ((lane * 8 + 1024) ^ sw)) = h2;
        *(ull*)(hsb + ((lane * 8 + 1536) ^ sw)) = h3;
      }
      __syncthreads();

      // D[m=outcol][n=batch] = sum_k W[outcol][k] * h[batch][k]
      // B-frag: lane (n=ar -> row a7 dup, k-grp hi) reads 16B
      const unsigned char* brow = hs + a7 * 2048;
      const int swb = a7 << 4;
#pragma unroll
      for (int kk = 0; kk < 32; kk += 2) {
        bf16x8 b0 = *(const bf16x8*)(brow + (((kk)     * 64 + hi * 16) ^ swb));
        bf16x8 b1 = *(const bf16x8*)(brow + (((kk + 1) * 64 + hi * 16) ^ swb));
        acc0 = __builtin_amdgcn_mfma_f32_16x16x32_bf16(Wreg[kk],     b0, acc0, 0, 0, 0);
        acc1 = __builtin_amdgcn_mfma_f32_16x16x32_bf16(Wreg[kk + 1], b1, acc1, 0, 0, 0);
      }
    }

    // epilogue: lane (batch=ar<8, colgrp=hi) owns cols wcol0+hi*4 .. +4
    if (ar < 8) {
      float hval[4];
#pragma unroll
      for (int reg = 0; reg < 4; reg++)
        hval[reg] = tanhf(acc0[reg] + acc1[reg] + xiv[reg]);
      ull hw = (ull)f2b(hval[0]) | ((ull)f2b(hval[1]) << 16) |
               ((ull)f2b(hval[2]) << 32) | ((ull)f2b(hval[3]) << 48);
      ast64((ull*)(hn + (size_t)(row0 + ar) * H_ + wcol0 + hi * 4), hw);
      if (t == T_ - 1) {
        float4_t o = {hval[0], hval[1], hval[2], hval[3]};
        *(float4_t*)(out_h + (size_t)(row0 + ar) * H_ + wcol0 + hi * 4) = o;
      }
    }

    // order: drain own stores, block barrier, signal (R5-proven)
    asm volatile("s_waitcnt vmcnt(0)" ::: "memory");
    __syncthreads();
    if (tid == 0)
      ast32(&gflags[j], (u32)(t + 1));
  }
}

// ---------------- logits = h_final @ W_cls^T + b ----------------
// grid 500 blocks (64 vocab cols each), 256 threads
__global__ __launch_bounds__(256)
void k_logits(const unsigned short* __restrict__ hb,
              const float* __restrict__ Wcls, const float* __restrict__ bcls,
              float* __restrict__ out) {
  __shared__ unsigned char Bs[64 * 128];
  const int tid = threadIdx.x;
  const int lane = tid & 63;
  const int w = tid >> 6;
  const int n0 = blockIdx.x * 64;
  f32x4 acc[4];
#pragma unroll
  for (int i = 0; i < 4; i++) acc[i] = (f32x4)0.0f;

  for (int kc = 0; kc < H_ / BK; kc++) {
    const int k0 = kc * BK;
    __syncthreads();
#pragma unroll
    for (int it = 0; it < 2; it++) {
      int idx = tid + it * 256;
      int r = idx >> 3;
      int k = (idx & 7) * 8;
      float tmp[8];
      *(float4_t*)(tmp)     = *(const float4_t*)(Wcls + (size_t)(n0 + r) * H_ + k0 + k);
      *(float4_t*)(tmp + 4) = *(const float4_t*)(Wcls + (size_t)(n0 + r) * H_ + k0 + k + 4);
      *(bf16x8*)(Bs + swz128(r, k * 2)) = cvt8(tmp);
    }
    __syncthreads();
#pragma unroll
    for (int kk = 0; kk < 2; kk++) {
      const unsigned short* ap =
          hb + (size_t)(w * 16 + (lane & 15)) * H_ + k0 + kk * 32 + (lane >> 4) * 8;
      bf16x8 a = *(const bf16x8*)ap;
      int kb = kk * 64 + (lane >> 4) * 16;
#pragma unroll
      for (int nt = 0; nt < 4; nt++) {
        bf16x8 b = *(const bf16x8*)(Bs + swz128(nt * 16 + (lane & 15), kb));
        acc[nt] = __builtin_amdgcn_mfma_f32_16x16x32_bf16(a, b, acc[nt], 0, 0, 0);
      }
    }
  }
#pragma unroll
  for (int nt = 0; nt < 4; nt++) {
    int col = n0 + nt * 16 + (lane & 15);
    float bias = bcls[col];
#pragma unroll
    for (int reg = 0; reg < 4; reg++) {
      int row = w * 16 + (lane >> 4) * 4 + reg;
      out[(size_t)row * V_ + col] = acc[nt][reg] + bias;
    }
  }
}

extern "C" void kernel_launch(void* const* d_in, const int* in_sizes, int n_in,
                              void* d_out, int out_size, void* d_ws, size_t ws_size,
                              hipStream_t stream) {
  const int*   hist = (const int*)d_in[0];
  const float* emb  = (const float*)d_in[1];
  const float* Wih  = (const float*)d_in[2];
  const float* Whh  = (const float*)d_in[3];
  const float* Wcls = (const float*)d_in[4];
  const float* bcls = (const float*)d_in[5];
  float* out = (float*)d_out;

  unsigned char* ws = (unsigned char*)d_ws;
  const size_t E2_BYTES = (size_t)V_ * H_ * 2;        // 65,536,000
  const size_t HB_BYTES = (size_t)B_ * H_ * 2;        // 131,072
  unsigned short* E2    = (unsigned short*)ws;
  unsigned short* hb0   = (unsigned short*)(ws + E2_BYTES);
  unsigned short* hb1   = (unsigned short*)(ws + E2_BYTES + HB_BYTES);
  u32*            flags = (u32*)(ws + E2_BYTES + 2 * HB_BYTES);

  k_init<<<1, 256, 0, stream>>>(flags);
  k_e2<<<dim3(16, 500), 256, 0, stream>>>(emb, Wih, E2);
  // T_=512: last write (t=511, odd) lands in hb0 -> k_logits reads hb0
  k_scan<<<64, 512, 0, stream>>>(hist, Whh, E2, hb0, hb1, flags,
                                 out + (size_t)B_ * V_);
  k_logits<<<500, 256, 0, stream>>>(hb0, Wcls, bcls, out);
}

// Round 11
// 1517.739 us; speedup vs baseline: 2.2312x; 1.0769x over previous
//
#include <hip/hip_runtime.h>
#include <hip/hip_bf16.h>
#include <cstdint>
#include <cstddef>

#define B_ 64
#define T_ 512
#define E_ 512
#define H_ 1024
#define V_ 32000
#define BK 64

typedef __attribute__((ext_vector_type(8))) short bf16x8;
typedef __attribute__((ext_vector_type(4))) float f32x4;
typedef __attribute__((ext_vector_type(4))) float float4_t;
typedef unsigned long long ull;
typedef unsigned int u32;

static __device__ __forceinline__ unsigned short f2b(float f) {
  union { float f; u32 u; } v; v.f = f;
  u32 u = v.u;
  u32 r = (u + 0x7FFFu + ((u >> 16) & 1u)) >> 16;  // RNE
  return (unsigned short)r;
}
static __device__ __forceinline__ float b2f(unsigned short s) {
  union { u32 u; float f; } v; v.u = ((u32)s) << 16;
  return v.f;
}
static __device__ __forceinline__ bf16x8 cvt8(const float* p) {
  bf16x8 r;
#pragma unroll
  for (int i = 0; i < 8; i++) r[i] = (short)f2b(p[i]);
  return r;
}
// relaxed agent-scope (sc1) ops: coherent at MALL, no cache maintenance
static __device__ __forceinline__ ull ald(const ull* p) {
  return __hip_atomic_load(p, __ATOMIC_RELAXED, __HIP_MEMORY_SCOPE_AGENT);
}
static __device__ __forceinline__ void ast64(ull* p, ull v) {
  __hip_atomic_store(p, v, __ATOMIC_RELAXED, __HIP_MEMORY_SCOPE_AGENT);
}
static __device__ __forceinline__ void ast32(u32* p, u32 v) {
  __hip_atomic_store(p, v, __ATOMIC_RELAXED, __HIP_MEMORY_SCOPE_AGENT);
}
// LDS swizzle for 128-byte rows: spread rows across banks
static __device__ __forceinline__ int swz128(int row, int byte_off) {
  return row * 128 + (byte_off ^ ((row & 7) << 4));
}

// ---------------- init: clear epoch-tagged exchange buffers ----------------
// MUST run every launch: tags surviving a graph replay would short-circuit
// the waits (forbidden cross-call state). 3*64*1024 = 196608 u32.
__global__ void k_init(u32* xb) {
  int i = blockIdx.x * blockDim.x + threadIdx.x;
  ast32(xb + i, 0u);
}

// ---------------- E2 = emb @ W_ih^T  [V,H] bf16 ----------------
// grid (16, 500), 256 threads, 64x64 tile, BK=64
__global__ __launch_bounds__(256)
void k_e2(const float* __restrict__ emb, const float* __restrict__ Wih,
          unsigned short* __restrict__ E2) {
  __shared__ unsigned char As[64 * 128];
  __shared__ unsigned char Bs[64 * 128];
  const int tid = threadIdx.x;
  const int lane = tid & 63;
  const int w = tid >> 6;
  const int n0 = blockIdx.x * 64;
  const int m0 = blockIdx.y * 64;
  f32x4 acc[4];
#pragma unroll
  for (int i = 0; i < 4; i++) acc[i] = (f32x4)0.0f;

  for (int kc = 0; kc < E_ / BK; kc++) {
    const int k0 = kc * BK;
    __syncthreads();
#pragma unroll
    for (int it = 0; it < 2; it++) {
      int idx = tid + it * 256;
      int r = idx >> 3;
      int k = (idx & 7) * 8;
      float tmp[8];
      *(float4_t*)(tmp)     = *(const float4_t*)(emb + (size_t)(m0 + r) * E_ + k0 + k);
      *(float4_t*)(tmp + 4) = *(const float4_t*)(emb + (size_t)(m0 + r) * E_ + k0 + k + 4);
      *(bf16x8*)(As + swz128(r, k * 2)) = cvt8(tmp);
      *(float4_t*)(tmp)     = *(const float4_t*)(Wih + (size_t)(n0 + r) * E_ + k0 + k);
      *(float4_t*)(tmp + 4) = *(const float4_t*)(Wih + (size_t)(n0 + r) * E_ + k0 + k + 4);
      *(bf16x8*)(Bs + swz128(r, k * 2)) = cvt8(tmp);
    }
    __syncthreads();
#pragma unroll
    for (int kk = 0; kk < 2; kk++) {
      int kb = kk * 64 + (lane >> 4) * 16;
      bf16x8 a = *(const bf16x8*)(As + swz128(w * 16 + (lane & 15), kb));
#pragma unroll
      for (int nt = 0; nt < 4; nt++) {
        bf16x8 b = *(const bf16x8*)(Bs + swz128(nt * 16 + (lane & 15), kb));
        acc[nt] = __builtin_amdgcn_mfma_f32_16x16x32_bf16(a, b, acc[nt], 0, 0, 0);
      }
    }
  }
#pragma unroll
  for (int nt = 0; nt < 4; nt++) {
#pragma unroll
    for (int reg = 0; reg < 4; reg++) {
      int row = m0 + w * 16 + (lane >> 4) * 4 + reg;
      int col = n0 + nt * 16 + (lane & 15);
      E2[(size_t)row * H_ + col] = f2b(acc[nt][reg]);
    }
  }
}

// ---------------- persistent scan over T ----------------
// R10 geometry: 8 groups x 8 blocks x 8 waves. Group g owns batch rows
// [8g,8g+8); block j owns h-cols [128j,128j+128); wave w owns 16 cols
// (Wreg 128 VGPR). R11 protocol: EPOCH-TAGGED exchange — h word =
// (t+1)<<16 | bf16, sc1-stored; the pull IS the poll (retry until all
// 16 tags/lane fresh). No drain, no flags, no epilogue barrier: chain =
// producer store flight + consumer retry-pull (1 RTT).
// Deadlock/WAR (triple buffer, 2-hop proof): wave@t writes buf[t%3];
// pull(t) success => all 64 group waves wrote tag t => each passed
// pull(t-1) => all waves passed pull(t-2) = the only other readers of
// buf[t%3]. LDS single-buffer + one barrier/step: stage(t+1) is gated on
// pull(t+1) => every same-block wave's write(t) => its MFMA(t) done.
// Barrier count uniform (t=0 skips uniformly). Only sc1 atomics (R8 lesson:
// no new visibility assumptions).
__global__ __launch_bounds__(512, 1)
void k_scan(const int* __restrict__ hist, const float* __restrict__ Whh,
            const unsigned short* __restrict__ E2,
            u32* __restrict__ xb,         // [3][64][1024] tagged words
            unsigned short* __restrict__ hbf, float* __restrict__ out_h) {
  const int tid = threadIdx.x;
  const int lane = tid & 63;
  const int w = tid >> 6;                 // wave id 0..7
  const int bid = blockIdx.x;
  const int g = bid & 7;                  // group (batch rows 8g..8g+8)
  const int j = bid >> 3;                 // col-slice id 0..7
  const int row0 = g * 8;                 // global batch-row base
  const int wcol0 = j * 128 + w * 16;     // this wave's 16 output cols

  __shared__ unsigned char hs[8 * 2048];  // h slice [8 rows][1024] bf16, swz

  const int ar = lane & 15;               // frag row: outcol (A) / batch (B,D)
  const int a7 = ar & 7;                  // valid batch row index
  const int hi = lane >> 4;               // 0..3 k-group

  // W-frags (MFMA A): lane holds W_hh[wcol0+ar][kk*32 + hi*8 .. +8)
  bf16x8 Wreg[32];
  {
    const float* wrow = Whh + (size_t)(wcol0 + ar) * H_ + hi * 8;
#pragma unroll
    for (int kk = 0; kk < 32; kk++) {
      float tmp[8];
      *(float4_t*)(tmp)     = *(const float4_t*)(wrow + kk * 32);
      *(float4_t*)(tmp + 4) = *(const float4_t*)(wrow + kk * 32 + 4);
      Wreg[kk] = cvt8(tmp);
    }
  }

  for (int t = 0; t < T_; t++) {
    // xi gather: ONE 8B load per lane — E2[tok][wcol0 + hi*4 .. +4)
    // (issued before the pull; latency hides under retries)
    float xiv[4];
    {
      const int tok = hist[(size_t)(row0 + a7) * T_ + t];
      const ull xw = *(const ull*)(E2 + (size_t)tok * H_ + wcol0 + hi * 4);
      xiv[0] = b2f((unsigned short)xw);
      xiv[1] = b2f((unsigned short)(xw >> 16));
      xiv[2] = b2f((unsigned short)(xw >> 32));
      xiv[3] = b2f((unsigned short)(xw >> 48));
    }

    f32x4 acc0 = (f32x4)0.0f, acc1 = (f32x4)0.0f;

    if (t > 0) {
      // ---- self-validating pull: wave w pulls row row0+w of buf[(t-1)%3]
      // (1024 tagged u32 = 512 ull; lane reads ull lane+64i, i=0..7) ----
      const u32* rbuf = xb + (size_t)((t + 2) % 3) * (B_ * H_);
      const ull* src = (const ull*)(rbuf + (size_t)(row0 + w) * H_);
      const u32 tagv = (u32)t << 16;
      ull hv[8];
      for (;;) {
#pragma unroll
        for (int i = 0; i < 8; i++) hv[i] = ald(src + lane + 64 * i);
        u32 bad = 0;
#pragma unroll
        for (int i = 0; i < 8; i++)
          bad |= (((u32)hv[i] ^ tagv) | ((u32)(hv[i] >> 32) ^ tagv)) &
                 0xFFFF0000u;
        if (__all(bad == 0)) break;
        __builtin_amdgcn_s_sleep(1);
      }
      // strip tags, stage to LDS (same layout/swizzle as R10)
      {
        unsigned char* hsb = hs + w * 2048;
        const int sw = w << 4;
#pragma unroll
        for (int i = 0; i < 8; i++) {
          u32 p = ((u32)hv[i] & 0xFFFFu) | ((u32)(hv[i] >> 32) << 16);
          *(u32*)(hsb + ((lane * 4 + i * 256) ^ sw)) = p;
        }
      }
      __syncthreads();

      // D[m=outcol][n=batch] = sum_k W[outcol][k] * h[batch][k]
      const unsigned char* brow = hs + a7 * 2048;
      const int swb = a7 << 4;
#pragma unroll
      for (int kk = 0; kk < 32; kk += 2) {
        bf16x8 b0 = *(const bf16x8*)(brow + (((kk)     * 64 + hi * 16) ^ swb));
        bf16x8 b1 = *(const bf16x8*)(brow + (((kk + 1) * 64 + hi * 16) ^ swb));
        acc0 = __builtin_amdgcn_mfma_f32_16x16x32_bf16(Wreg[kk],     b0, acc0, 0, 0, 0);
        acc1 = __builtin_amdgcn_mfma_f32_16x16x32_bf16(Wreg[kk + 1], b1, acc1, 0, 0, 0);
      }
    }

    // epilogue: tagged store — fire-and-forget (store IS the signal)
    if (ar < 8) {
      float hval[4];
#pragma unroll
      for (int reg = 0; reg < 4; reg++)
        hval[reg] = tanhf(acc0[reg] + acc1[reg] + xiv[reg]);
      const u32 tagw = (u32)(t + 1) << 16;
      ull lo = (ull)(tagw | f2b(hval[0])) | ((ull)(tagw | f2b(hval[1])) << 32);
      ull hi2 = (ull)(tagw | f2b(hval[2])) | ((ull)(tagw | f2b(hval[3])) << 32);
      u32* wbuf = xb + (size_t)(t % 3) * (B_ * H_);
      ull* dst = (ull*)(wbuf + (size_t)(row0 + ar) * H_ + wcol0 + hi * 4);
      ast64(dst, lo);
      ast64(dst + 1, hi2);
      if (t == T_ - 1) {
        float4_t o = {hval[0], hval[1], hval[2], hval[3]};
        *(float4_t*)(out_h + (size_t)(row0 + ar) * H_ + wcol0 + hi * 4) = o;
        unsigned short* hp = hbf + (size_t)(row0 + ar) * H_ + wcol0 + hi * 4;
        hp[0] = f2b(hval[0]); hp[1] = f2b(hval[1]);
        hp[2] = f2b(hval[2]); hp[3] = f2b(hval[3]);
      }
    }
  }
}

// ---------------- logits = h_final @ W_cls^T + b ----------------
// grid 500 blocks (64 vocab cols each), 256 threads
__global__ __launch_bounds__(256)
void k_logits(const unsigned short* __restrict__ hb,
              const float* __restrict__ Wcls, const float* __restrict__ bcls,
              float* __restrict__ out) {
  __shared__ unsigned char Bs[64 * 128];
  const int tid = threadIdx.x;
  const int lane = tid & 63;
  const int w = tid >> 6;
  const int n0 = blockIdx.x * 64;
  f32x4 acc[4];
#pragma unroll
  for (int i = 0; i < 4; i++) acc[i] = (f32x4)0.0f;

  for (int kc = 0; kc < H_ / BK; kc++) {
    const int k0 = kc * BK;
    __syncthreads();
#pragma unroll
    for (int it = 0; it < 2; it++) {
      int idx = tid + it * 256;
      int r = idx >> 3;
      int k = (idx & 7) * 8;
      float tmp[8];
      *(float4_t*)(tmp)     = *(const float4_t*)(Wcls + (size_t)(n0 + r) * H_ + k0 + k);
      *(float4_t*)(tmp + 4) = *(const float4_t*)(Wcls + (size_t)(n0 + r) * H_ + k0 + k + 4);
      *(bf16x8*)(Bs + swz128(r, k * 2)) = cvt8(tmp);
    }
    __syncthreads();
#pragma unroll
    for (int kk = 0; kk < 2; kk++) {
      const unsigned short* ap =
          hb + (size_t)(w * 16 + (lane & 15)) * H_ + k0 + kk * 32 + (lane >> 4) * 8;
      bf16x8 a = *(const bf16x8*)ap;
      int kb = kk * 64 + (lane >> 4) * 16;
#pragma unroll
      for (int nt = 0; nt < 4; nt++) {
        bf16x8 b = *(const bf16x8*)(Bs + swz128(nt * 16 + (lane & 15), kb));
        acc[nt] = __builtin_amdgcn_mfma_f32_16x16x32_bf16(a, b, acc[nt], 0, 0, 0);
      }
    }
  }
#pragma unroll
  for (int nt = 0; nt < 4; nt++) {
    int col = n0 + nt * 16 + (lane & 15);
    float bias = bcls[col];
#pragma unroll
    for (int reg = 0; reg < 4; reg++) {
      int row = w * 16 + (lane >> 4) * 4 + reg;
      out[(size_t)row * V_ + col] = acc[nt][reg] + bias;
    }
  }
}

extern "C" void kernel_launch(void* const* d_in, const int* in_sizes, int n_in,
                              void* d_out, int out_size, void* d_ws, size_t ws_size,
                              hipStream_t stream) {
  const int*   hist = (const int*)d_in[0];
  const float* emb  = (const float*)d_in[1];
  const float* Wih  = (const float*)d_in[2];
  const float* Whh  = (const float*)d_in[3];
  const float* Wcls = (const float*)d_in[4];
  const float* bcls = (const float*)d_in[5];
  float* out = (float*)d_out;

  unsigned char* ws = (unsigned char*)d_ws;
  const size_t E2_BYTES = (size_t)V_ * H_ * 2;        // 65,536,000
  const size_t XB_BYTES = (size_t)3 * B_ * H_ * 4;    // 786,432
  unsigned short* E2  = (unsigned short*)ws;
  u32*            xbf = (u32*)(ws + E2_BYTES);
  unsigned short* hbf = (unsigned short*)(ws + E2_BYTES + XB_BYTES);

  k_init<<<768, 256, 0, stream>>>(xbf);
  k_e2<<<dim3(16, 500), 256, 0, stream>>>(emb, Wih, E2);
  k_scan<<<64, 512, 0, stream>>>(hist, Whh, E2, xbf, hbf,
                                 out + (size_t)B_ * V_);
  k_logits<<<500, 256, 0, stream>>>(hbf, Wcls, bcls, out);
}